// Round 6
// baseline (111.503 us; speedup 1.0000x reference)
//
#include <hip/hip_runtime.h>
#include <math.h>

#define EDIM 512
#define LDIM 128
#define MTOT 16384   // 8*2048 tokens
#define TM 16        // rows per block
#define BK 64        // k-chunk
#define NCHUNK 8
#define LSTR 76      // A LDS row stride in shorts (152 B -> rotated banks)

typedef __attribute__((ext_vector_type(8))) short s8v;    // 8 bf16 MFMA frag
typedef __attribute__((ext_vector_type(4))) short s4v;
typedef __attribute__((ext_vector_type(4))) float f4v;

__device__ __forceinline__ unsigned short f2bf(float x) {
    union { float f; unsigned u; } c; c.f = x;
    return (unsigned short)((c.u + 0x7fffu + ((c.u >> 16) & 1u)) >> 16);  // RNE
}

// ---- prep: Bfrag = bf16(means*inv_var) pre-packed fragment-LINEAR:
// short addr = kc*8192 + F*512 + lane*8, F = ks_i*8 + ct,
// element (col=(F&7)*16+(lane&15), k=kc*64+(F>>3)*32+(lane>>4)*8+j).
// Also m2[l], inv_var, coef.  (verified in R5: absmax 8.0)
__global__ __launch_bounds__(64) void gs_prep(
    const float* __restrict__ means, const float* __restrict__ var,
    unsigned short* __restrict__ Bfrag, float* __restrict__ m2,
    float* __restrict__ ivbuf, float* __restrict__ coef)
{
    const int l = blockIdx.x;    // 0..127 (= col = ct*16 + fr)
    const int t = threadIdx.x;   // 0..63  (= kc*8 + ks_i*4 + q)
    const int e0 = t * 8;

    float mv[8], iv[8];
    const float* mrow = means + l * EDIM + e0;
#pragma unroll
    for (int i = 0; i < 8; ++i) { mv[i] = mrow[i]; iv[i] = 1.0f / var[e0 + i]; }

    float part = 0.0f;
    s8v pr;
#pragma unroll
    for (int i = 0; i < 8; ++i) {
        float p = mv[i] * iv[i];            // means * inv_var
        pr[i] = (short)f2bf(p);
        part += mv[i] * p;                  // means^2 * inv_var
    }
    {
        const int kc   = t >> 3;
        const int ks_i = (t >> 2) & 1;
        const int q    = t & 3;
        const int F    = ks_i * 8 + (l >> 4);
        const int ln   = q * 16 + (l & 15);
        *(s8v*)(Bfrag + kc * 8192 + F * 512 + ln * 8) = pr;
    }

#pragma unroll
    for (int off = 32; off > 0; off >>= 1) part += __shfl_down(part, off, 64);
    if (t == 0) m2[l] = part;

    if (l == 0) {
#pragma unroll
        for (int i = 0; i < 8; ++i) ivbuf[e0 + i] = iv[i];
        float ld = 0.0f;
#pragma unroll
        for (int i = 0; i < 8; ++i) ld += logf(var[e0 + i]);
#pragma unroll
        for (int off = 32; off > 0; off >>= 1) ld += __shfl_down(ld, off, 64);
        if (t == 0) {
            const float factor = -(float)EDIM * 0.5f * 1.8378770664093453f; // ln(2*pi)
            *coef = factor - 0.5f * ld;
        }
    }
}

// ---- main: BARRIER-FREE K-loop. 1024 blocks x 4 waves; wave w owns the
// block's 16 rows x cols [w*32, w*32+32). B-frags: registers, coalesced from
// fragment-linear Bfrag (depth-2 ring). A: wave-PRIVATE load+convert+LDS
// round-trip (intra-wave lgkmcnt ordering only - no s_barrier => no vmcnt(0)
// drain; all waits are fine-grained compiler register-dep waitcnts).
__global__ __launch_bounds__(256, 4) void gs_main(
    const float* __restrict__ emb, const unsigned short* __restrict__ Bfrag,
    const float* __restrict__ m2, const float* __restrict__ ivbuf,
    const float* __restrict__ coef, float* __restrict__ out)
{
    __shared__ __align__(16) unsigned short Alds[4][2][TM][LSTR];  // 19456 B

    const int t    = threadIdx.x;
    const int lane = t & 63;
    const int w    = t >> 6;          // wave 0..3
    const int q    = lane >> 4;       // quad (= row-group h)
    const int fr   = lane & 15;
    const int m0   = blockIdx.x * TM;

    // A load map: seg s covers row q*4+s, k-window fr*4..fr*4+3 (per chunk).
    // => lane's e2 partials are exactly its 4 C-layout output rows q*4+s.
    const float* ap  = emb + ((size_t)m0 + q * 4) * EDIM + fr * 4;
    const float* ivp = ivbuf + fr * 4;

#define LOAD_A(kc, slot)                                                   \
    {                                                                      \
        _Pragma("unroll")                                                  \
        for (int s = 0; s < 4; ++s)                                        \
            ax[slot][s] = *(const f4v*)(ap + s * EDIM + (kc) * BK);        \
        vx[slot] = *(const f4v*)(ivp + (kc) * BK);                         \
    }

#define LOAD_B(kc, slot)                                                   \
    {                                                                      \
        _Pragma("unroll")                                                  \
        for (int ks = 0; ks < 2; ++ks)                                     \
            _Pragma("unroll")                                              \
            for (int j = 0; j < 2; ++j)                                    \
                bx[slot][ks][j] = *(const s8v*)(Bfrag + (kc) * 8192        \
                                   + (ks * 8 + w * 2 + j) * 512 + lane * 8); \
    }

#define CVT_A(slot)                                                        \
    {                                                                      \
        _Pragma("unroll")                                                  \
        for (int s = 0; s < 4; ++s) {                                      \
            s4v a4;                                                        \
            _Pragma("unroll")                                              \
            for (int i = 0; i < 4; ++i) {                                  \
                const float x = ax[slot][s][i];                            \
                a4[i] = (short)f2bf(x);                                    \
                e2p[s] += x * x * vx[slot][i];                             \
            }                                                              \
            *(s4v*)&Alds[w][slot][q * 4 + s][fr * 4] = a4;                 \
        }                                                                  \
    }

    f4v acc[2];
    acc[0] = (f4v)0.0f; acc[1] = (f4v)0.0f;
    float e2p[4] = {0.0f, 0.0f, 0.0f, 0.0f};

    f4v ax[2][4];          // A raw ring, depth 2
    f4v vx[2];             // iv ring
    s8v bx[2][2][2];       // B frag ring, depth 2

    LOAD_A(0, 0)
    LOAD_B(0, 0)
    LOAD_A(1, 1)
    LOAD_B(1, 1)
    CVT_A(0)               // chunk 0 -> Alds buf 0

#pragma unroll
    for (int kc = 0; kc < NCHUNK; ++kc) {
        const int b = kc & 1;

        // prefetch A(kc+2) into slot b (chunk kc's A already converted)
        if (kc + 2 < NCHUNK) LOAD_A(kc + 2, b)

        // convert chunk kc+1 (loads are 1 chunk old) -> Alds buf !b
        if (kc + 1 < NCHUNK) CVT_A(!b)

        // MFMA chunk kc: A frags from Alds buf b (written iter kc-1),
        // B frags from registers (loaded iter kc-2)
#pragma unroll
        for (int ks = 0; ks < 2; ++ks) {
            s8v af = *(const s8v*)&Alds[w][b][fr][ks * 32 + q * 8];
#pragma unroll
            for (int j = 0; j < 2; ++j)
                acc[j] = __builtin_amdgcn_mfma_f32_16x16x32_bf16(af, bx[b][ks][j], acc[j], 0, 0, 0);
        }

        // prefetch B(kc+2) into slot b (just consumed)
        if (kc + 2 < NCHUNK) LOAD_B(kc + 2, b)
    }

    // e2: reduce k-window partials across the 16 lanes of this row-group
#pragma unroll
    for (int s = 0; s < 4; ++s) {
        e2p[s] += __shfl_xor(e2p[s], 1, 64);
        e2p[s] += __shfl_xor(e2p[s], 2, 64);
        e2p[s] += __shfl_xor(e2p[s], 4, 64);
        e2p[s] += __shfl_xor(e2p[s], 8, 64);
    }

    const float cf = *coef;
#pragma unroll
    for (int j = 0; j < 2; ++j) {
        const int n = (w * 2 + j) * 16 + fr;
        const float cm = cf - 0.5f * m2[n];
#pragma unroll
        for (int r = 0; r < 4; ++r) {
            const int row = q * 4 + r;     // C/D: col=lane&15, row=quad*4+reg
            out[(size_t)(m0 + row) * LDIM + n] = acc[j][r] + cm - 0.5f * e2p[r];
        }
    }
#undef LOAD_A
#undef LOAD_B
#undef CVT_A
}

extern "C" void kernel_launch(void* const* d_in, const int* in_sizes, int n_in,
                              void* d_out, int out_size, void* d_ws, size_t ws_size,
                              hipStream_t stream) {
    const float* emb   = (const float*)d_in[0];
    const float* means = (const float*)d_in[1];
    const float* var   = (const float*)d_in[2];
    float* out = (float*)d_out;

    char* ws = (char*)d_ws;
    unsigned short* Bfrag = (unsigned short*)ws;         // 131072 B
    float* m2    = (float*)(ws + 131072);                // 512 B
    float* ivbuf = (float*)(ws + 131584);                // 2048 B
    float* coef  = (float*)(ws + 133632);                // 4 B

    gs_prep<<<LDIM, 64, 0, stream>>>(means, var, Bfrag, m2, ivbuf, coef);
    gs_main<<<MTOT / TM, 256, 0, stream>>>(emb, Bfrag, m2, ivbuf, coef, out);
}